// Round 18
// baseline (219.925 us; speedup 1.0000x reference)
//
#include <hip/hip_runtime.h>

typedef _Float16 f16;
typedef _Float16 f16x8 __attribute__((ext_vector_type(8)));
typedef float f32x4 __attribute__((ext_vector_type(4)));
typedef unsigned short u16;
typedef unsigned int u32;
typedef u32 u32x4 __attribute__((ext_vector_type(4)));

// ---- workspace layout (bytes) ----
#define WS_BN1_INV  256u
#define WS_BN1_BETA 1280u
#define WS_BN2_INV  2304u
#define WS_BN2_BETA 3328u
#define WS_BN3_INV  4352u
#define WS_BN3_BETA 8448u
#define WS_PEG_B    12544u
#define WS_PEGQ     13568u
#define WS_W1Q      18432u
#define WS_W3Q      542720u
#define WS_W2Q      1067008u
#define WS_H1T      2246656u
#define WS_H2T      19023872u

// r11: act fake-quant subsumed by f16 rounding. r14: conv1 dbuf. r15: conv2+3
// fused. r17: low-bit LDS swizzle. r18: conv23 at 64-px tiles / 68KB LDS ->
// grid 512 = 2 blocks/CU, so one block's phase-2 stream overlaps the other's
// phase-1 MFMAs (cross-block overlap; within-block prefetch failed in r16).

__device__ __forceinline__ int badf(float f){
  union { float f; u32 u; } c; c.f = f;
  return (c.u & 0x7f800000u) == 0x7f800000u;
}
__device__ __forceinline__ float qpow2(float w){
  float a = fabsf(w) + 1e-20f;
  float p = rintf(log2f(a));
  p = fminf(fmaxf(p, -14.0f), 0.0f);
  float m = exp2f(p);
  return (w > 0.0f) ? m : ((w < 0.0f) ? -m : 0.0f);
}
__device__ __forceinline__ u32 pack2(float a, float b){
  union { f16 h[2]; u32 u; } p; p.h[0] = (f16)a; p.h[1] = (f16)b; return p.u;
}
#define SWZ(row, slot) ((((slot) ^ ((row) >> 1) ^ ((row) >> 3))) & 3)

// ---- prep ----
__global__ __launch_bounds__(256) void prep_kernel(
    const float* __restrict__ w1, const float* __restrict__ pegw, const float* __restrict__ pegb,
    const float* __restrict__ w2, const float* __restrict__ w3,
    const float* g1, const float* b1, const float* m1, const float* v1,
    const float* g2, const float* b2, const float* m2, const float* v2,
    const float* g3, const float* b3, const float* m3, const float* v3,
    char* ws){
  int i = blockIdx.x * 256 + threadIdx.x;
  if (i < 262144){ ((f16*)(ws + WS_W1Q))[i] = (f16)qpow2(w1[i]); return; }
  i -= 262144;
  if (i < 589824){
    int tap = i >> 16, rem = i & 65535;
    int co = rem >> 8, ci = rem & 255;
    ((f16*)(ws + WS_W2Q))[i] = (f16)qpow2(w2[(((co << 8) + ci) * 9) + tap]);
    return;
  }
  i -= 589824;
  if (i < 262144){ ((f16*)(ws + WS_W3Q))[i] = (f16)qpow2(w3[i]); return; }
  i -= 262144;
  if (i < 2304){
    int tap = i >> 8, c = i & 255;
    ((f16*)(ws + WS_PEGQ))[i] = (f16)qpow2(pegw[c * 9 + tap]);
    return;
  }
  i -= 2304;
  if (i < 256){ ((float*)(ws + WS_PEG_B))[i] = pegb[i]; return; }
  i -= 256;
  if (i < 256){
    float inv = g1[i] / sqrtf(v1[i] + 1e-5f);
    ((float*)(ws + WS_BN1_INV))[i] = inv;
    ((float*)(ws + WS_BN1_BETA))[i] = b1[i] - m1[i] * inv;
    return;
  }
  i -= 256;
  if (i < 256){
    float inv = g2[i] / sqrtf(v2[i] + 1e-5f);
    ((float*)(ws + WS_BN2_INV))[i] = inv;
    ((float*)(ws + WS_BN2_BETA))[i] = b2[i] - m2[i] * inv;
    return;
  }
  i -= 256;
  if (i < 1024){
    float inv = g3[i] / sqrtf(v3[i] + 1e-5f);
    ((float*)(ws + WS_BN3_INV))[i] = inv;
    ((float*)(ws + WS_BN3_BETA))[i] = b3[i] - m3[i] * inv;
  }
}

// ---- conv1: 1x1 1024->256, 128px x 256co, dbuf single-barrier (r14) ----
__global__ __launch_bounds__(512) void conv1_kernel(const float* __restrict__ x, char* ws){
  __shared__ __align__(16) char lds[49152];
  const f16* w1q = (const f16*)(ws + WS_W1Q);
  f16* h1T = (f16*)(ws + WS_H1T);

  int tid = threadIdx.x, bid = blockIdx.x;
  int b = bid >> 3, m0 = (bid & 7) << 7;
  int l = tid & 63, wid = tid >> 6, wm = wid >> 2, wn = wid & 3;
  int lr = l & 15, lg = l >> 4;
  f32x4 acc[4][4] = {};

  int q = tid & 31;
  int c = tid >> 5;
  const float* xb = x + (((size_t)(b << 10)) << 10) + m0 + (q << 2);
  int aslot = c >> 2, aoff = (c & 3) << 2;

  f32x4 d0, d1; u32x4 wb0, wb1;
  {
    const float* src = xb + (((size_t)(c << 1)) << 10);
    d0 = *(const f32x4*)src;
    d1 = *(const f32x4*)(src + 1024);
    int s0 = tid, r0 = s0 >> 2, sl0 = s0 & 3;
    int s1 = tid + 512, r1 = s1 >> 2, sl1 = s1 & 3;
    wb0 = *(const u32x4*)(w1q + ((size_t)r0 << 10) + (sl0 << 3));
    wb1 = *(const u32x4*)(w1q + ((size_t)r1 << 10) + (sl1 << 3));
  }
  {
    char* A = lds;
    #pragma unroll
    for (int j = 0; j < 4; ++j){
      int row = (q << 2) + j;
      *(u32*)(A + (row << 6) + (SWZ(row, aslot) << 4) + aoff) = pack2(d0[j], d1[j]);
    }
    int s0 = tid, r0 = s0 >> 2, sl0 = s0 & 3;
    int s1 = tid + 512, r1 = s1 >> 2, sl1 = s1 & 3;
    *(u32x4*)(lds + 8192 + (r0 << 6) + (SWZ(r0, sl0) << 4)) = wb0;
    *(u32x4*)(lds + 8192 + (r1 << 6) + (SWZ(r1, sl1) << 4)) = wb1;
  }
  __syncthreads();

  for (int ks = 0; ks < 32; ++ks){
    const char* cur = lds + ((ks & 1) ? 24576 : 0);
    char* nxt = lds + ((ks & 1) ? 0 : 24576);
    if (ks < 31){
      int k0 = (ks + 1) << 5;
      const float* src = xb + (((size_t)(k0 + (c << 1))) << 10);
      d0 = *(const f32x4*)src;
      d1 = *(const f32x4*)(src + 1024);
      int s0 = tid, r0 = s0 >> 2, sl0 = s0 & 3;
      int s1 = tid + 512, r1 = s1 >> 2, sl1 = s1 & 3;
      wb0 = *(const u32x4*)(w1q + ((size_t)r0 << 10) + k0 + (sl0 << 3));
      wb1 = *(const u32x4*)(w1q + ((size_t)r1 << 10) + k0 + (sl1 << 3));
    }
    f16x8 a[4], bb[4];
    #pragma unroll
    for (int mf = 0; mf < 4; ++mf){
      int row = (wm << 6) + (mf << 4) + lr;
      a[mf] = *(const f16x8*)(cur + (row << 6) + (SWZ(row, lg) << 4));
    }
    #pragma unroll
    for (int nf = 0; nf < 4; ++nf){
      int row = (wn << 6) + (nf << 4) + lr;
      bb[nf] = *(const f16x8*)(cur + 8192 + (row << 6) + (SWZ(row, lg) << 4));
    }
    #pragma unroll
    for (int mf = 0; mf < 4; ++mf)
      #pragma unroll
      for (int nf = 0; nf < 4; ++nf)
        acc[mf][nf] = __builtin_amdgcn_mfma_f32_16x16x32_f16(a[mf], bb[nf], acc[mf][nf], 0, 0, 0);
    if (ks < 31){
      #pragma unroll
      for (int j = 0; j < 4; ++j){
        int row = (q << 2) + j;
        *(u32*)(nxt + (row << 6) + (SWZ(row, aslot) << 4) + aoff) = pack2(d0[j], d1[j]);
      }
      int s0 = tid, r0 = s0 >> 2, sl0 = s0 & 3;
      int s1 = tid + 512, r1 = s1 >> 2, sl1 = s1 & 3;
      *(u32x4*)(nxt + 8192 + (r0 << 6) + (SWZ(r0, sl0) << 4)) = wb0;
      *(u32x4*)(nxt + 8192 + (r1 << 6) + (SWZ(r1, sl1) << 4)) = wb1;
    }
    __syncthreads();
  }

  #pragma unroll
  for (int mf = 0; mf < 4; ++mf){
    int p0 = m0 + (wm << 6) + (mf << 4) + (lg << 2);
    size_t base = ((size_t)(b << 10) + p0) << 8;
    #pragma unroll
    for (int nf = 0; nf < 4; ++nf){
      int co = (wn << 6) + (nf << 4) + lr;
      #pragma unroll
      for (int r = 0; r < 4; ++r)
        h1T[base + ((size_t)r << 8) + co] = (f16)acc[mf][nf][r];
    }
  }
}

// ---- PEG: depthwise 3x3 ----
__global__ __launch_bounds__(256) void peg_kernel(char* ws){
  __shared__ __align__(16) f16 tile[3][32][256];
  const f16* h1T = (const f16*)(ws + WS_H1T);
  const f16* pegq = (const f16*)(ws + WS_PEGQ);
  const float* pb  = (const float*)(ws + WS_PEG_B);
  const float* inv1 = (const float*)(ws + WS_BN1_INV);
  const float* bt1  = (const float*)(ws + WS_BN1_BETA);
  f16* h2T = (f16*)(ws + WS_H2T);

  int tid = threadIdx.x;
  int b = blockIdx.x >> 5, h = blockIdx.x & 31;

  #pragma unroll
  for (int r = 0; r < 3; ++r){
    int hh = h + r - 1;
    #pragma unroll
    for (int i = 0; i < 4; ++i){
      int chunk = tid + (i << 8);
      int px = chunk >> 5, cg = chunk & 31;
      u32x4 d = {0u, 0u, 0u, 0u};
      if ((u32)hh < 32u)
        d = *(const u32x4*)(h1T + (((size_t)(b << 10) + (hh << 5) + px) << 8) + (cg << 3));
      *(u32x4*)(&tile[r][px][cg << 3]) = d;
    }
  }
  __syncthreads();

  int c0 = (tid & 31) << 3;
  int q  = tid >> 5;
  float acc[4][8];
  #pragma unroll
  for (int i = 0; i < 4; ++i)
    #pragma unroll
    for (int j = 0; j < 8; ++j) acc[i][j] = pb[c0 + j];

  #pragma unroll
  for (int ky = 0; ky < 3; ++ky){
    #pragma unroll
    for (int kx = 0; kx < 3; ++kx){
      f16x8 wv = *(const f16x8*)(pegq + ((ky * 3 + kx) << 8) + c0);
      #pragma unroll
      for (int i = 0; i < 4; ++i){
        int ww = (q << 2) + i + kx - 1;
        if ((u32)ww < 32u){
          f16x8 v = *(const f16x8*)(&tile[ky][ww][c0]);
          #pragma unroll
          for (int j = 0; j < 8; ++j) acc[i][j] += (float)v[j] * (float)wv[j];
        }
      }
    }
  }

  f32x4 iv0 = *(const f32x4*)(inv1 + c0), iv1 = *(const f32x4*)(inv1 + c0 + 4);
  f32x4 bt0 = *(const f32x4*)(bt1 + c0),  bt1v = *(const f32x4*)(bt1 + c0 + 4);
  #pragma unroll
  for (int i = 0; i < 4; ++i){
    f16x8 o;
    #pragma unroll
    for (int j = 0; j < 8; ++j){
      float ivj = (j < 4) ? iv0[j] : iv1[j - 4];
      float btj = (j < 4) ? bt0[j] : bt1v[j - 4];
      o[j] = (f16)fmaxf(acc[i][j] * ivj + btj, 0.0f);
    }
    int p = (h << 5) + (q << 2) + i;
    *(f16x8*)(h2T + (((size_t)(b << 10) + p) << 8) + c0) = o;
  }
}

// ---- conv23 (FUSED, 64px tiles, 68KB LDS, grid 512 -> 2 blocks/CU):
// phase 1: conv2 (A = [4 rows][34 cols][128 ci] per K-half, restaged; B 16KB
// single-buffer); h3 -> LDS; phase 2: conv3 over 16 co-tiles of 64. ----
__global__ __launch_bounds__(512) void conv23_kernel(const float* __restrict__ x,
                                                     float* __restrict__ out, char* ws){
  __shared__ __align__(16) char lds[69632];  // [0,36864): A then h3 ; [36864,69632): B then w3
  const f16* h2T = (const f16*)(ws + WS_H2T);
  const f16* w2q = (const f16*)(ws + WS_W2Q);
  const f16* w3q = (const f16*)(ws + WS_W3Q);
  const float* inv2 = (const float*)(ws + WS_BN2_INV);
  const float* bt2  = (const float*)(ws + WS_BN2_BETA);
  const float* inv3 = (const float*)(ws + WS_BN3_INV);
  const float* bt3  = (const float*)(ws + WS_BN3_BETA);

  int tid = threadIdx.x, bid = blockIdx.x;
  int b = bid >> 4, mt = bid & 15;
  int h0 = mt << 1;             // first image row (2 rows per tile)
  int m0 = mt << 6;             // first pixel
  int l = tid & 63, wid = tid >> 6, wm = wid >> 2, wn = wid & 3;
  int lr = l & 15, lg = l >> 4;
  int rk = lr & 7;
  char* B = lds + 36864;

  // ===== phase 1: conv2, K in 2 halves; A restaged per half =====
  f32x4 acc[2][4] = {};
  u32x4 st[2];
  // prefetch B for step (kh=0, tap=0, ks4=0)
  #pragma unroll
  for (int i = 0; i < 2; ++i){
    int chunk = tid + (i << 9);
    int co = chunk >> 2, slot = chunk & 3;
    st[i] = *(const u32x4*)(w2q + (co << 8) + (slot << 3));
  }

  for (int kh = 0; kh < 2; ++kh){
    __syncthreads();   // all reads of A (prev half) done before restage
    // stage A: [4 rows][34 cols][128 ci] f16, 256B rows, low-bit swizzle
    for (int chunk = tid; chunk < 2176; chunk += 512){
      int r = chunk / 544;
      int rem = chunk - r * 544;
      int cc = rem >> 4, slot = rem & 15;
      int hh = h0 - 1 + r, wwp = cc - 1;
      u32x4 d = {0u, 0u, 0u, 0u};
      if ((u32)hh < 32u && (u32)wwp < 32u)
        d = *(const u32x4*)(h2T + (((size_t)(b << 10) + (hh << 5) + wwp) << 8) + (kh << 7) + (slot << 3));
      *(u32x4*)(lds + ((r * 34 + cc) << 8) + ((slot ^ (cc & 7)) << 4)) = d;
    }
    for (int tap = 0; tap < 9; ++tap){
      int dy = tap / 3 - 1, dx = tap % 3 - 1;
      int rowbase[2], key[2];
      #pragma unroll
      for (int mf = 0; mf < 2; ++mf){
        int p = (wm << 5) + (mf << 4) + lr;
        int rr = (p >> 5) + dy + 1;
        int cc = (p & 31) + dx + 1;
        rowbase[mf] = (rr * 34 + cc) << 8;
        key[mf] = cc & 7;
      }
      for (int ks4 = 0; ks4 < 4; ++ks4){
        __syncthreads();             // all reads of B(prev) done (covers A stage too)
        #pragma unroll
        for (int i = 0; i < 2; ++i){
          int chunk = tid + (i << 9);
          int co = chunk >> 2, slot = chunk & 3;
          *(u32x4*)(B + (co << 6) + (SWZ(co, slot) << 4)) = st[i];
        }
        __syncthreads();             // B ready
        // prefetch next step's B
        int nkh = kh, ntap = tap, nks4 = ks4 + 1, have = 1;
        if (nks4 == 4){ nks4 = 0; ntap = tap + 1;
          if (ntap == 9){ ntap = 0; nkh = kh + 1; if (nkh == 2) have = 0; } }
        if (have){
          const f16* srcb = w2q + ntap * 65536 + (nkh << 7) + (nks4 << 5);
          #pragma unroll
          for (int i = 0; i < 2; ++i){
            int chunk = tid + (i << 9);
            int co = chunk >> 2, slot = chunk & 3;
            st[i] = *(const u32x4*)(srcb + (co << 8) + (slot << 3));
          }
        }
        // fragments + MFMA
        int sl = (ks4 << 2) | lg;
        f16x8 a[2], bb[4];
        #pragma unroll
        for (int mf = 0; mf < 2; ++mf)
          a[mf] = *(const f16x8*)(lds + rowbase[mf] + ((sl ^ key[mf]) << 4));
        #pragma unroll
        for (int nf = 0; nf < 4; ++nf){
          int row = (wn << 6) + (nf << 4) + lr;
          bb[nf] = *(const f16x8*)(B + (row << 6) + (SWZ(row, lg) << 4));
        }
        #pragma unroll
        for (int mf = 0; mf < 2; ++mf)
          #pragma unroll
          for (int nf = 0; nf < 4; ++nf)
            acc[mf][nf] = __builtin_amdgcn_mfma_f32_16x16x32_f16(a[mf], bb[nf], acc[mf][nf], 0, 0, 0);
      }
    }
  }

  __syncthreads();   // A reads done before h3 overwrite

  // ===== h3 = bn2+relu(acc) -> LDS [64 px][256 c], 512B rows, low-bit swz =====
  #pragma unroll
  for (int mf = 0; mf < 2; ++mf){
    #pragma unroll
    for (int nf = 0; nf < 4; ++nf){
      int c = (wn << 6) + (nf << 4) + lr;
      float iv = inv2[c], bt = bt2[c];
      int slot = c >> 3, off = (c & 7) << 1;
      #pragma unroll
      for (int r = 0; r < 4; ++r){
        int px = (wm << 5) + (mf << 4) + (lg << 2) + r;
        float f = fmaxf(acc[mf][nf][r] * iv + bt, 0.0f);
        *(f16*)(lds + (px << 9) + ((slot ^ (px & 7)) << 4) + off) = (f16)f;
      }
    }
  }

  // ===== phase 2: conv3 over 16 co-tiles of 64; wc = co-half, wp = px-quad =====
  int wc = wid >> 2, wp = wid & 3;
  for (int cot = 0; cot < 16; ++cot){
    // stage w3 tile [64 co][256 ci] -> B region (32KB), 512B rows, low-bit swz
    #pragma unroll
    for (int i = 0; i < 4; ++i){
      int chunk = (tid << 2) + i;
      int row = chunk >> 5, slot = chunk & 31;
      u32x4 d = *(const u32x4*)(w3q + (((size_t)(cot << 6) + row) << 8) + (slot << 3));
      *(u32x4*)(B + (row << 9) + ((slot ^ (row & 7)) << 4)) = d;
    }
    __syncthreads();   // w3 ready + (first iter) h3 visible

    f32x4 acc2[2] = {};
    #pragma unroll
    for (int ks = 0; ks < 8; ++ks){
      int sl = ((ks << 2) | lg) ^ rk;
      f16x8 a[2], bb;
      #pragma unroll
      for (int mf = 0; mf < 2; ++mf){
        int row = (wc << 5) + (mf << 4) + lr;
        a[mf] = *(const f16x8*)(B + (row << 9) + (sl << 4));
      }
      {
        int row = (wp << 4) + lr;
        bb = *(const f16x8*)(lds + (row << 9) + (sl << 4));
      }
      #pragma unroll
      for (int mf = 0; mf < 2; ++mf)
        acc2[mf] = __builtin_amdgcn_mfma_f32_16x16x32_f16(a[mf], bb, acc2[mf], 0, 0, 0);
    }

    // epilogue: bn3 + residual + relu -> out
    #pragma unroll
    for (int mf = 0; mf < 2; ++mf){
      int co0 = (cot << 6) + (wc << 5) + (mf << 4) + (lg << 2);
      f32x4 iv = *(const f32x4*)(inv3 + co0);
      f32x4 bt = *(const f32x4*)(bt3 + co0);
      int px = (wp << 4) + lr;
      float xr[4];
      #pragma unroll
      for (int r = 0; r < 4; ++r)
        xr[r] = x[(((size_t)(b << 10) + co0 + r) << 10) + m0 + px];
      #pragma unroll
      for (int r = 0; r < 4; ++r){
        size_t idx = (((size_t)(b << 10) + co0 + r) << 10) + m0 + px;
        float z = acc2[mf][r] * iv[r] + bt[r] + xr[r];
        float rr = fmaxf(z, 0.0f);
        if (badf(z)) rr = 512.0f;
        out[idx] = rr;
      }
    }
    __syncthreads();   // all reads done before next w3 stage
  }
}

extern "C" void kernel_launch(void* const* d_in, const int* in_sizes, int n_in,
                              void* d_out, int out_size, void* d_ws, size_t ws_size,
                              hipStream_t stream){
  const float* x    = (const float*)d_in[0];
  const float* w1   = (const float*)d_in[1];
  const float* pegw = (const float*)d_in[2];
  const float* pegb = (const float*)d_in[3];
  const float* w2   = (const float*)d_in[4];
  const float* w3   = (const float*)d_in[5];
  const float* g1 = (const float*)d_in[6];
  const float* b1 = (const float*)d_in[7];
  const float* m1 = (const float*)d_in[8];
  const float* v1 = (const float*)d_in[9];
  const float* g2 = (const float*)d_in[10];
  const float* b2 = (const float*)d_in[11];
  const float* m2 = (const float*)d_in[12];
  const float* v2 = (const float*)d_in[13];
  const float* g3 = (const float*)d_in[14];
  const float* b3 = (const float*)d_in[15];
  const float* m3 = (const float*)d_in[16];
  const float* v3 = (const float*)d_in[17];
  char* ws = (char*)d_ws;

  prep_kernel<<<4368, 256, 0, stream>>>(w1, pegw, pegb, w2, w3,
                                        g1, b1, m1, v1, g2, b2, m2, v2,
                                        g3, b3, m3, v3, ws);
  conv1_kernel<<<256, 512, 0, stream>>>(x, ws);
  peg_kernel<<<1024, 256, 0, stream>>>(ws);
  conv23_kernel<<<512, 512, 0, stream>>>(x, (float*)d_out, ws);
}

// Round 19
// 188.933 us; speedup vs baseline: 1.1640x; 1.1640x over previous
//
#include <hip/hip_runtime.h>

typedef _Float16 f16;
typedef _Float16 f16x8 __attribute__((ext_vector_type(8)));
typedef float f32x4 __attribute__((ext_vector_type(4)));
typedef unsigned short u16;
typedef unsigned int u32;
typedef u32 u32x4 __attribute__((ext_vector_type(4)));

// ---- workspace layout (bytes) ----
#define WS_BN1_INV  256u
#define WS_BN1_BETA 1280u
#define WS_BN2_INV  2304u
#define WS_BN2_BETA 3328u
#define WS_BN3_INV  4352u
#define WS_BN3_BETA 8448u
#define WS_PEG_B    12544u
#define WS_PEGQ     13568u
#define WS_W1Q      18432u
#define WS_W3Q      542720u
#define WS_W2Q      1067008u
#define WS_H1T      2246656u
#define WS_H2T      19023872u

// r11: act fake-quant subsumed by f16 rounding. r14: conv1 dbuf. r15: conv2+3
// fused. r17: low-bit LDS swizzle (conv23 123us, best). r18: 64px/2-block
// variant regressed (177us; occupancy did NOT double, conflicts 2.5x) —
// r19: reverted to r17 shape + non-temporal x loads in epilogue (x is
// read-once; keep L2 for h2T/w2q/w3q).

__device__ __forceinline__ int badf(float f){
  union { float f; u32 u; } c; c.f = f;
  return (c.u & 0x7f800000u) == 0x7f800000u;
}
__device__ __forceinline__ float qpow2(float w){
  float a = fabsf(w) + 1e-20f;
  float p = rintf(log2f(a));
  p = fminf(fmaxf(p, -14.0f), 0.0f);
  float m = exp2f(p);
  return (w > 0.0f) ? m : ((w < 0.0f) ? -m : 0.0f);
}
__device__ __forceinline__ u32 pack2(float a, float b){
  union { f16 h[2]; u32 u; } p; p.h[0] = (f16)a; p.h[1] = (f16)b; return p.u;
}
#define SWZ(row, slot) ((((slot) ^ ((row) >> 1) ^ ((row) >> 3))) & 3)

// ---- prep: quantize all weights to f16 pow2, precompute BN affine ----
__global__ __launch_bounds__(256) void prep_kernel(
    const float* __restrict__ w1, const float* __restrict__ pegw, const float* __restrict__ pegb,
    const float* __restrict__ w2, const float* __restrict__ w3,
    const float* g1, const float* b1, const float* m1, const float* v1,
    const float* g2, const float* b2, const float* m2, const float* v2,
    const float* g3, const float* b3, const float* m3, const float* v3,
    char* ws){
  int i = blockIdx.x * 256 + threadIdx.x;
  if (i < 262144){ ((f16*)(ws + WS_W1Q))[i] = (f16)qpow2(w1[i]); return; }
  i -= 262144;
  if (i < 589824){
    int tap = i >> 16, rem = i & 65535;
    int co = rem >> 8, ci = rem & 255;
    ((f16*)(ws + WS_W2Q))[i] = (f16)qpow2(w2[(((co << 8) + ci) * 9) + tap]);
    return;
  }
  i -= 589824;
  if (i < 262144){ ((f16*)(ws + WS_W3Q))[i] = (f16)qpow2(w3[i]); return; }
  i -= 262144;
  if (i < 2304){
    int tap = i >> 8, c = i & 255;
    ((f16*)(ws + WS_PEGQ))[i] = (f16)qpow2(pegw[c * 9 + tap]);
    return;
  }
  i -= 2304;
  if (i < 256){ ((float*)(ws + WS_PEG_B))[i] = pegb[i]; return; }
  i -= 256;
  if (i < 256){
    float inv = g1[i] / sqrtf(v1[i] + 1e-5f);
    ((float*)(ws + WS_BN1_INV))[i] = inv;
    ((float*)(ws + WS_BN1_BETA))[i] = b1[i] - m1[i] * inv;
    return;
  }
  i -= 256;
  if (i < 256){
    float inv = g2[i] / sqrtf(v2[i] + 1e-5f);
    ((float*)(ws + WS_BN2_INV))[i] = inv;
    ((float*)(ws + WS_BN2_BETA))[i] = b2[i] - m2[i] * inv;
    return;
  }
  i -= 256;
  if (i < 1024){
    float inv = g3[i] / sqrtf(v3[i] + 1e-5f);
    ((float*)(ws + WS_BN3_INV))[i] = inv;
    ((float*)(ws + WS_BN3_BETA))[i] = b3[i] - m3[i] * inv;
  }
}

// ---- conv1: 1x1 1024->256, 128px x 256co, dbuf single-barrier (r14) ----
__global__ __launch_bounds__(512) void conv1_kernel(const float* __restrict__ x, char* ws){
  __shared__ __align__(16) char lds[49152];
  const f16* w1q = (const f16*)(ws + WS_W1Q);
  f16* h1T = (f16*)(ws + WS_H1T);

  int tid = threadIdx.x, bid = blockIdx.x;
  int b = bid >> 3, m0 = (bid & 7) << 7;
  int l = tid & 63, wid = tid >> 6, wm = wid >> 2, wn = wid & 3;
  int lr = l & 15, lg = l >> 4;
  f32x4 acc[4][4] = {};

  int q = tid & 31;
  int c = tid >> 5;
  const float* xb = x + (((size_t)(b << 10)) << 10) + m0 + (q << 2);
  int aslot = c >> 2, aoff = (c & 3) << 2;

  f32x4 d0, d1; u32x4 wb0, wb1;
  {
    const float* src = xb + (((size_t)(c << 1)) << 10);
    d0 = *(const f32x4*)src;
    d1 = *(const f32x4*)(src + 1024);
    int s0 = tid, r0 = s0 >> 2, sl0 = s0 & 3;
    int s1 = tid + 512, r1 = s1 >> 2, sl1 = s1 & 3;
    wb0 = *(const u32x4*)(w1q + ((size_t)r0 << 10) + (sl0 << 3));
    wb1 = *(const u32x4*)(w1q + ((size_t)r1 << 10) + (sl1 << 3));
  }
  {
    char* A = lds;
    #pragma unroll
    for (int j = 0; j < 4; ++j){
      int row = (q << 2) + j;
      *(u32*)(A + (row << 6) + (SWZ(row, aslot) << 4) + aoff) = pack2(d0[j], d1[j]);
    }
    int s0 = tid, r0 = s0 >> 2, sl0 = s0 & 3;
    int s1 = tid + 512, r1 = s1 >> 2, sl1 = s1 & 3;
    *(u32x4*)(lds + 8192 + (r0 << 6) + (SWZ(r0, sl0) << 4)) = wb0;
    *(u32x4*)(lds + 8192 + (r1 << 6) + (SWZ(r1, sl1) << 4)) = wb1;
  }
  __syncthreads();

  for (int ks = 0; ks < 32; ++ks){
    const char* cur = lds + ((ks & 1) ? 24576 : 0);
    char* nxt = lds + ((ks & 1) ? 0 : 24576);
    if (ks < 31){
      int k0 = (ks + 1) << 5;
      const float* src = xb + (((size_t)(k0 + (c << 1))) << 10);
      d0 = *(const f32x4*)src;
      d1 = *(const f32x4*)(src + 1024);
      int s0 = tid, r0 = s0 >> 2, sl0 = s0 & 3;
      int s1 = tid + 512, r1 = s1 >> 2, sl1 = s1 & 3;
      wb0 = *(const u32x4*)(w1q + ((size_t)r0 << 10) + k0 + (sl0 << 3));
      wb1 = *(const u32x4*)(w1q + ((size_t)r1 << 10) + k0 + (sl1 << 3));
    }
    f16x8 a[4], bb[4];
    #pragma unroll
    for (int mf = 0; mf < 4; ++mf){
      int row = (wm << 6) + (mf << 4) + lr;
      a[mf] = *(const f16x8*)(cur + (row << 6) + (SWZ(row, lg) << 4));
    }
    #pragma unroll
    for (int nf = 0; nf < 4; ++nf){
      int row = (wn << 6) + (nf << 4) + lr;
      bb[nf] = *(const f16x8*)(cur + 8192 + (row << 6) + (SWZ(row, lg) << 4));
    }
    #pragma unroll
    for (int mf = 0; mf < 4; ++mf)
      #pragma unroll
      for (int nf = 0; nf < 4; ++nf)
        acc[mf][nf] = __builtin_amdgcn_mfma_f32_16x16x32_f16(a[mf], bb[nf], acc[mf][nf], 0, 0, 0);
    if (ks < 31){
      #pragma unroll
      for (int j = 0; j < 4; ++j){
        int row = (q << 2) + j;
        *(u32*)(nxt + (row << 6) + (SWZ(row, aslot) << 4) + aoff) = pack2(d0[j], d1[j]);
      }
      int s0 = tid, r0 = s0 >> 2, sl0 = s0 & 3;
      int s1 = tid + 512, r1 = s1 >> 2, sl1 = s1 & 3;
      *(u32x4*)(nxt + 8192 + (r0 << 6) + (SWZ(r0, sl0) << 4)) = wb0;
      *(u32x4*)(nxt + 8192 + (r1 << 6) + (SWZ(r1, sl1) << 4)) = wb1;
    }
    __syncthreads();
  }

  #pragma unroll
  for (int mf = 0; mf < 4; ++mf){
    int p0 = m0 + (wm << 6) + (mf << 4) + (lg << 2);
    size_t base = ((size_t)(b << 10) + p0) << 8;
    #pragma unroll
    for (int nf = 0; nf < 4; ++nf){
      int co = (wn << 6) + (nf << 4) + lr;
      #pragma unroll
      for (int r = 0; r < 4; ++r)
        h1T[base + ((size_t)r << 8) + co] = (f16)acc[mf][nf][r];
    }
  }
}

// ---- PEG: depthwise 3x3, block = one (batch,row); pure-copy staging ----
__global__ __launch_bounds__(256) void peg_kernel(char* ws){
  __shared__ __align__(16) f16 tile[3][32][256];
  const f16* h1T = (const f16*)(ws + WS_H1T);
  const f16* pegq = (const f16*)(ws + WS_PEGQ);
  const float* pb  = (const float*)(ws + WS_PEG_B);
  const float* inv1 = (const float*)(ws + WS_BN1_INV);
  const float* bt1  = (const float*)(ws + WS_BN1_BETA);
  f16* h2T = (f16*)(ws + WS_H2T);

  int tid = threadIdx.x;
  int b = blockIdx.x >> 5, h = blockIdx.x & 31;

  #pragma unroll
  for (int r = 0; r < 3; ++r){
    int hh = h + r - 1;
    #pragma unroll
    for (int i = 0; i < 4; ++i){
      int chunk = tid + (i << 8);
      int px = chunk >> 5, cg = chunk & 31;
      u32x4 d = {0u, 0u, 0u, 0u};
      if ((u32)hh < 32u)
        d = *(const u32x4*)(h1T + (((size_t)(b << 10) + (hh << 5) + px) << 8) + (cg << 3));
      *(u32x4*)(&tile[r][px][cg << 3]) = d;
    }
  }
  __syncthreads();

  int c0 = (tid & 31) << 3;
  int q  = tid >> 5;
  float acc[4][8];
  #pragma unroll
  for (int i = 0; i < 4; ++i)
    #pragma unroll
    for (int j = 0; j < 8; ++j) acc[i][j] = pb[c0 + j];

  #pragma unroll
  for (int ky = 0; ky < 3; ++ky){
    #pragma unroll
    for (int kx = 0; kx < 3; ++kx){
      f16x8 wv = *(const f16x8*)(pegq + ((ky * 3 + kx) << 8) + c0);
      #pragma unroll
      for (int i = 0; i < 4; ++i){
        int ww = (q << 2) + i + kx - 1;
        if ((u32)ww < 32u){
          f16x8 v = *(const f16x8*)(&tile[ky][ww][c0]);
          #pragma unroll
          for (int j = 0; j < 8; ++j) acc[i][j] += (float)v[j] * (float)wv[j];
        }
      }
    }
  }

  f32x4 iv0 = *(const f32x4*)(inv1 + c0), iv1 = *(const f32x4*)(inv1 + c0 + 4);
  f32x4 bt0 = *(const f32x4*)(bt1 + c0),  bt1v = *(const f32x4*)(bt1 + c0 + 4);
  #pragma unroll
  for (int i = 0; i < 4; ++i){
    f16x8 o;
    #pragma unroll
    for (int j = 0; j < 8; ++j){
      float ivj = (j < 4) ? iv0[j] : iv1[j - 4];
      float btj = (j < 4) ? bt0[j] : bt1v[j - 4];
      o[j] = (f16)fmaxf(acc[i][j] * ivj + btj, 0.0f);
    }
    int p = (h << 5) + (q << 2) + i;
    *(f16x8*)(h2T + (((size_t)(b << 10) + p) << 8) + c0) = o;
  }
}

// ---- conv23 (FUSED, r17 shape): conv2 (h3 in LDS) + conv3 + bn3 + residual
// + relu. 512B-row tiles with low-bit swizzle; NT loads on read-once x. ----
__global__ __launch_bounds__(512) void conv23_kernel(const float* __restrict__ x,
                                                     float* __restrict__ out, char* ws){
  __shared__ __align__(16) char lds[137216];
  const f16* h2T = (const f16*)(ws + WS_H2T);
  const f16* w2q = (const f16*)(ws + WS_W2Q);
  const f16* w3q = (const f16*)(ws + WS_W3Q);
  const float* inv2 = (const float*)(ws + WS_BN2_INV);
  const float* bt2  = (const float*)(ws + WS_BN2_BETA);
  const float* inv3 = (const float*)(ws + WS_BN3_INV);
  const float* bt3  = (const float*)(ws + WS_BN3_BETA);

  int tid = threadIdx.x, bid = blockIdx.x;
  int b = bid >> 3, mt = bid & 7;
  int h0 = mt << 2;
  int m0 = mt << 7;
  int l = tid & 63, wid = tid >> 6, wm = wid >> 2, wn = wid & 3;
  int lr = l & 15, lg = l >> 4;
  int rk = lr & 7;
  char* A = lds;
  char* B0 = lds + 104448;
  char* B1 = lds + 104448 + 16384;

  // ===== phase 1: conv2 (A staged once, low-bit swizzle; B dbuf 64B rows) =====
  for (int chunk = tid; chunk < 6528; chunk += 512){
    int r = chunk / 1088;
    int rem = chunk - r * 1088;
    int cc = rem >> 5, slot = rem & 31;
    int hh = h0 - 1 + r, wwp = cc - 1;
    u32x4 d = {0u, 0u, 0u, 0u};
    if ((u32)hh < 32u && (u32)wwp < 32u)
      d = *(const u32x4*)(h2T + (((size_t)(b << 10) + (hh << 5) + wwp) << 8) + (slot << 3));
    int sw = slot ^ (cc & 7);
    *(u32x4*)(A + ((r * 34 + cc) << 9) + (sw << 4)) = d;
  }
  #pragma unroll
  for (int i = 0; i < 2; ++i){
    int chunk = tid + (i << 9);
    int co = chunk >> 2, slot = chunk & 3;
    u32x4 d = *(const u32x4*)(w2q + (co << 8) + (slot << 3));
    *(u32x4*)(B0 + (co << 6) + (SWZ(co, slot) << 4)) = d;
  }
  __syncthreads();

  f32x4 acc[4][4] = {};
  for (int tap = 0; tap < 9; ++tap){
    int dy = tap / 3 - 1, dx = tap % 3 - 1;
    int rowbase[4], key[4];
    #pragma unroll
    for (int mf = 0; mf < 4; ++mf){
      int p = (wm << 6) + (mf << 4) + lr;
      int rr = (p >> 5) + dy + 1;
      int cc = (p & 31) + dx + 1;
      rowbase[mf] = (rr * 34 + cc) << 9;
      key[mf] = cc & 7;
    }
    #pragma unroll 2
    for (int ks = 0; ks < 8; ++ks){
      int t = (tap << 3) + ks;
      u32x4 st[2];
      int have = (t < 71);
      int t1 = t + 1, wtap = t1 >> 3, wks = t1 & 7;
      const f16* srcb = w2q + wtap * 65536 + (wks << 5);
      if (have){
        #pragma unroll
        for (int i = 0; i < 2; ++i){
          int chunk = tid + (i << 9);
          int co = chunk >> 2, slot = chunk & 3;
          st[i] = *(const u32x4*)(srcb + (co << 8) + (slot << 3));
        }
      }
      const char* bs = (t & 1) ? B1 : B0;
      f16x8 a[4], bb[4];
      int sl = (ks << 2) | lg;
      #pragma unroll
      for (int mf = 0; mf < 4; ++mf)
        a[mf] = *(const f16x8*)(A + rowbase[mf] + ((sl ^ key[mf]) << 4));
      #pragma unroll
      for (int nf = 0; nf < 4; ++nf){
        int row = (wn << 6) + (nf << 4) + lr;
        bb[nf] = *(const f16x8*)(bs + (row << 6) + (SWZ(row, lg) << 4));
      }
      #pragma unroll
      for (int mf = 0; mf < 4; ++mf)
        #pragma unroll
        for (int nf = 0; nf < 4; ++nf)
          acc[mf][nf] = __builtin_amdgcn_mfma_f32_16x16x32_f16(a[mf], bb[nf], acc[mf][nf], 0, 0, 0);
      if (have){
        char* bd = (t1 & 1) ? B1 : B0;
        #pragma unroll
        for (int i = 0; i < 2; ++i){
          int chunk = tid + (i << 9);
          int co = chunk >> 2, slot = chunk & 3;
          *(u32x4*)(bd + (co << 6) + (SWZ(co, slot) << 4)) = st[i];
        }
      }
      __syncthreads();
    }
  }

  // ===== h3 = bn2+relu(acc) -> LDS [128 px][256 c], low-bit swizzle =====
  #pragma unroll
  for (int mf = 0; mf < 4; ++mf){
    #pragma unroll
    for (int nf = 0; nf < 4; ++nf){
      int c = (wn << 6) + (nf << 4) + lr;
      float iv = inv2[c], bt = bt2[c];
      int slot = c >> 3, off = (c & 7) << 1;
      #pragma unroll
      for (int r = 0; r < 4; ++r){
        int px = (wm << 6) + (mf << 4) + (lg << 2) + r;
        float f = fmaxf(acc[mf][nf][r] * iv + bt, 0.0f);
        *(f16*)(lds + (px << 9) + ((slot ^ (px & 7)) << 4) + off) = (f16)f;
      }
    }
  }
  __syncthreads();

  // ===== phase 2: conv3, 8 co-tiles; h3 + w3 in LDS (low-bit swizzle) =====
  for (int cot = 0; cot < 8; ++cot){
    #pragma unroll
    for (int i = 0; i < 8; ++i){
      int s = tid + (i << 9);
      int row = s >> 5, slot = s & 31;
      u32x4 d = *(const u32x4*)(w3q + (((size_t)(cot << 7) + row) << 8) + (slot << 3));
      *(u32x4*)(lds + 65536 + (row << 9) + ((slot ^ (row & 7)) << 4)) = d;
    }
    __syncthreads();

    f32x4 acc2[4][2] = {};
    #pragma unroll
    for (int ks = 0; ks < 8; ++ks){
      int sl = ((ks << 2) | lg) ^ rk;
      f16x8 a[4], bb[2];
      #pragma unroll
      for (int mf = 0; mf < 4; ++mf){
        int row = (wm << 6) + (mf << 4) + lr;
        a[mf] = *(const f16x8*)(lds + 65536 + (row << 9) + (sl << 4));
      }
      #pragma unroll
      for (int nf = 0; nf < 2; ++nf){
        int row = (wn << 5) + (nf << 4) + lr;
        bb[nf] = *(const f16x8*)(lds + (row << 9) + (sl << 4));
      }
      #pragma unroll
      for (int mf = 0; mf < 4; ++mf)
        #pragma unroll
        for (int nf = 0; nf < 2; ++nf)
          acc2[mf][nf] = __builtin_amdgcn_mfma_f32_16x16x32_f16(a[mf], bb[nf], acc2[mf][nf], 0, 0, 0);
    }

    // epilogue: bn3 + residual + relu -> out (NT loads on read-once x)
    #pragma unroll
    for (int mf = 0; mf < 4; ++mf){
      int co0 = (cot << 7) + (wm << 6) + (mf << 4) + (lg << 2);
      f32x4 iv = *(const f32x4*)(inv3 + co0);
      f32x4 bt = *(const f32x4*)(bt3 + co0);
      float xr[8];
      #pragma unroll
      for (int nf = 0; nf < 2; ++nf){
        int px = (wn << 5) + (nf << 4) + lr;
        #pragma unroll
        for (int r = 0; r < 4; ++r)
          xr[(nf << 2) + r] = __builtin_nontemporal_load(
              &x[(((size_t)(b << 10) + co0 + r) << 10) + m0 + px]);
      }
      #pragma unroll
      for (int nf = 0; nf < 2; ++nf){
        int px = (wn << 5) + (nf << 4) + lr;
        #pragma unroll
        for (int r = 0; r < 4; ++r){
          size_t idx = (((size_t)(b << 10) + co0 + r) << 10) + m0 + px;
          float z = acc2[mf][nf][r] * iv[r] + bt[r] + xr[(nf << 2) + r];
          float rr = fmaxf(z, 0.0f);
          if (badf(z)) rr = 512.0f;
          out[idx] = rr;
        }
      }
    }
    __syncthreads();
  }
}

extern "C" void kernel_launch(void* const* d_in, const int* in_sizes, int n_in,
                              void* d_out, int out_size, void* d_ws, size_t ws_size,
                              hipStream_t stream){
  const float* x    = (const float*)d_in[0];
  const float* w1   = (const float*)d_in[1];
  const float* pegw = (const float*)d_in[2];
  const float* pegb = (const float*)d_in[3];
  const float* w2   = (const float*)d_in[4];
  const float* w3   = (const float*)d_in[5];
  const float* g1 = (const float*)d_in[6];
  const float* b1 = (const float*)d_in[7];
  const float* m1 = (const float*)d_in[8];
  const float* v1 = (const float*)d_in[9];
  const float* g2 = (const float*)d_in[10];
  const float* b2 = (const float*)d_in[11];
  const float* m2 = (const float*)d_in[12];
  const float* v2 = (const float*)d_in[13];
  const float* g3 = (const float*)d_in[14];
  const float* b3 = (const float*)d_in[15];
  const float* m3 = (const float*)d_in[16];
  const float* v3 = (const float*)d_in[17];
  char* ws = (char*)d_ws;

  prep_kernel<<<4368, 256, 0, stream>>>(w1, pegw, pegb, w2, w3,
                                        g1, b1, m1, v1, g2, b2, m2, v2,
                                        g3, b3, m3, v3, ws);
  conv1_kernel<<<256, 512, 0, stream>>>(x, ws);
  peg_kernel<<<1024, 256, 0, stream>>>(ws);
  conv23_kernel<<<256, 512, 0, stream>>>(x, (float*)d_out, ws);
}

// Round 20
// 169.167 us; speedup vs baseline: 1.3001x; 1.1168x over previous
//
#include <hip/hip_runtime.h>

typedef _Float16 f16;
typedef _Float16 f16x8 __attribute__((ext_vector_type(8)));
typedef float f32x4 __attribute__((ext_vector_type(4)));
typedef unsigned short u16;
typedef unsigned int u32;
typedef u32 u32x4 __attribute__((ext_vector_type(4)));

// ---- workspace layout (bytes) ----
#define WS_BN1_INV  256u
#define WS_BN1_BETA 1280u
#define WS_BN2_INV  2304u
#define WS_BN2_BETA 3328u
#define WS_BN3_INV  4352u
#define WS_BN3_BETA 8448u
#define WS_PEG_B    12544u
#define WS_PEGQ     13568u
#define WS_W1Q      18432u
#define WS_W3Q      542720u
#define WS_W2Q      1067008u
#define WS_H1T      2246656u
#define WS_H2T      19023872u

// r11: act fake-quant subsumed by f16 rounding. r14: conv1 dbuf. r15: conv2+3
// fused. r17: low-bit LDS swizzle. r18: 64px tiles regressed. r19: NT x-loads
// neutral-to-harmful (FETCH +7MB) — reverted. r20: phase-2 w3 DOUBLE-BUFFERED
// (16 co-tiles of 64, 32KB each): stage latency hides under MFMA+epilogue.

__device__ __forceinline__ int badf(float f){
  union { float f; u32 u; } c; c.f = f;
  return (c.u & 0x7f800000u) == 0x7f800000u;
}
__device__ __forceinline__ float qpow2(float w){
  float a = fabsf(w) + 1e-20f;
  float p = rintf(log2f(a));
  p = fminf(fmaxf(p, -14.0f), 0.0f);
  float m = exp2f(p);
  return (w > 0.0f) ? m : ((w < 0.0f) ? -m : 0.0f);
}
__device__ __forceinline__ u32 pack2(float a, float b){
  union { f16 h[2]; u32 u; } p; p.h[0] = (f16)a; p.h[1] = (f16)b; return p.u;
}
#define SWZ(row, slot) ((((slot) ^ ((row) >> 1) ^ ((row) >> 3))) & 3)

// ---- prep: quantize all weights to f16 pow2, precompute BN affine ----
__global__ __launch_bounds__(256) void prep_kernel(
    const float* __restrict__ w1, const float* __restrict__ pegw, const float* __restrict__ pegb,
    const float* __restrict__ w2, const float* __restrict__ w3,
    const float* g1, const float* b1, const float* m1, const float* v1,
    const float* g2, const float* b2, const float* m2, const float* v2,
    const float* g3, const float* b3, const float* m3, const float* v3,
    char* ws){
  int i = blockIdx.x * 256 + threadIdx.x;
  if (i < 262144){ ((f16*)(ws + WS_W1Q))[i] = (f16)qpow2(w1[i]); return; }
  i -= 262144;
  if (i < 589824){
    int tap = i >> 16, rem = i & 65535;
    int co = rem >> 8, ci = rem & 255;
    ((f16*)(ws + WS_W2Q))[i] = (f16)qpow2(w2[(((co << 8) + ci) * 9) + tap]);
    return;
  }
  i -= 589824;
  if (i < 262144){ ((f16*)(ws + WS_W3Q))[i] = (f16)qpow2(w3[i]); return; }
  i -= 262144;
  if (i < 2304){
    int tap = i >> 8, c = i & 255;
    ((f16*)(ws + WS_PEGQ))[i] = (f16)qpow2(pegw[c * 9 + tap]);
    return;
  }
  i -= 2304;
  if (i < 256){ ((float*)(ws + WS_PEG_B))[i] = pegb[i]; return; }
  i -= 256;
  if (i < 256){
    float inv = g1[i] / sqrtf(v1[i] + 1e-5f);
    ((float*)(ws + WS_BN1_INV))[i] = inv;
    ((float*)(ws + WS_BN1_BETA))[i] = b1[i] - m1[i] * inv;
    return;
  }
  i -= 256;
  if (i < 256){
    float inv = g2[i] / sqrtf(v2[i] + 1e-5f);
    ((float*)(ws + WS_BN2_INV))[i] = inv;
    ((float*)(ws + WS_BN2_BETA))[i] = b2[i] - m2[i] * inv;
    return;
  }
  i -= 256;
  if (i < 1024){
    float inv = g3[i] / sqrtf(v3[i] + 1e-5f);
    ((float*)(ws + WS_BN3_INV))[i] = inv;
    ((float*)(ws + WS_BN3_BETA))[i] = b3[i] - m3[i] * inv;
  }
}

// ---- conv1: 1x1 1024->256, 128px x 256co, dbuf single-barrier (r14) ----
__global__ __launch_bounds__(512) void conv1_kernel(const float* __restrict__ x, char* ws){
  __shared__ __align__(16) char lds[49152];
  const f16* w1q = (const f16*)(ws + WS_W1Q);
  f16* h1T = (f16*)(ws + WS_H1T);

  int tid = threadIdx.x, bid = blockIdx.x;
  int b = bid >> 3, m0 = (bid & 7) << 7;
  int l = tid & 63, wid = tid >> 6, wm = wid >> 2, wn = wid & 3;
  int lr = l & 15, lg = l >> 4;
  f32x4 acc[4][4] = {};

  int q = tid & 31;
  int c = tid >> 5;
  const float* xb = x + (((size_t)(b << 10)) << 10) + m0 + (q << 2);
  int aslot = c >> 2, aoff = (c & 3) << 2;

  f32x4 d0, d1; u32x4 wb0, wb1;
  {
    const float* src = xb + (((size_t)(c << 1)) << 10);
    d0 = *(const f32x4*)src;
    d1 = *(const f32x4*)(src + 1024);
    int s0 = tid, r0 = s0 >> 2, sl0 = s0 & 3;
    int s1 = tid + 512, r1 = s1 >> 2, sl1 = s1 & 3;
    wb0 = *(const u32x4*)(w1q + ((size_t)r0 << 10) + (sl0 << 3));
    wb1 = *(const u32x4*)(w1q + ((size_t)r1 << 10) + (sl1 << 3));
  }
  {
    char* A = lds;
    #pragma unroll
    for (int j = 0; j < 4; ++j){
      int row = (q << 2) + j;
      *(u32*)(A + (row << 6) + (SWZ(row, aslot) << 4) + aoff) = pack2(d0[j], d1[j]);
    }
    int s0 = tid, r0 = s0 >> 2, sl0 = s0 & 3;
    int s1 = tid + 512, r1 = s1 >> 2, sl1 = s1 & 3;
    *(u32x4*)(lds + 8192 + (r0 << 6) + (SWZ(r0, sl0) << 4)) = wb0;
    *(u32x4*)(lds + 8192 + (r1 << 6) + (SWZ(r1, sl1) << 4)) = wb1;
  }
  __syncthreads();

  for (int ks = 0; ks < 32; ++ks){
    const char* cur = lds + ((ks & 1) ? 24576 : 0);
    char* nxt = lds + ((ks & 1) ? 0 : 24576);
    if (ks < 31){
      int k0 = (ks + 1) << 5;
      const float* src = xb + (((size_t)(k0 + (c << 1))) << 10);
      d0 = *(const f32x4*)src;
      d1 = *(const f32x4*)(src + 1024);
      int s0 = tid, r0 = s0 >> 2, sl0 = s0 & 3;
      int s1 = tid + 512, r1 = s1 >> 2, sl1 = s1 & 3;
      wb0 = *(const u32x4*)(w1q + ((size_t)r0 << 10) + k0 + (sl0 << 3));
      wb1 = *(const u32x4*)(w1q + ((size_t)r1 << 10) + k0 + (sl1 << 3));
    }
    f16x8 a[4], bb[4];
    #pragma unroll
    for (int mf = 0; mf < 4; ++mf){
      int row = (wm << 6) + (mf << 4) + lr;
      a[mf] = *(const f16x8*)(cur + (row << 6) + (SWZ(row, lg) << 4));
    }
    #pragma unroll
    for (int nf = 0; nf < 4; ++nf){
      int row = (wn << 6) + (nf << 4) + lr;
      bb[nf] = *(const f16x8*)(cur + 8192 + (row << 6) + (SWZ(row, lg) << 4));
    }
    #pragma unroll
    for (int mf = 0; mf < 4; ++mf)
      #pragma unroll
      for (int nf = 0; nf < 4; ++nf)
        acc[mf][nf] = __builtin_amdgcn_mfma_f32_16x16x32_f16(a[mf], bb[nf], acc[mf][nf], 0, 0, 0);
    if (ks < 31){
      #pragma unroll
      for (int j = 0; j < 4; ++j){
        int row = (q << 2) + j;
        *(u32*)(nxt + (row << 6) + (SWZ(row, aslot) << 4) + aoff) = pack2(d0[j], d1[j]);
      }
      int s0 = tid, r0 = s0 >> 2, sl0 = s0 & 3;
      int s1 = tid + 512, r1 = s1 >> 2, sl1 = s1 & 3;
      *(u32x4*)(nxt + 8192 + (r0 << 6) + (SWZ(r0, sl0) << 4)) = wb0;
      *(u32x4*)(nxt + 8192 + (r1 << 6) + (SWZ(r1, sl1) << 4)) = wb1;
    }
    __syncthreads();
  }

  #pragma unroll
  for (int mf = 0; mf < 4; ++mf){
    int p0 = m0 + (wm << 6) + (mf << 4) + (lg << 2);
    size_t base = ((size_t)(b << 10) + p0) << 8;
    #pragma unroll
    for (int nf = 0; nf < 4; ++nf){
      int co = (wn << 6) + (nf << 4) + lr;
      #pragma unroll
      for (int r = 0; r < 4; ++r)
        h1T[base + ((size_t)r << 8) + co] = (f16)acc[mf][nf][r];
    }
  }
}

// ---- PEG: depthwise 3x3, block = one (batch,row); pure-copy staging ----
__global__ __launch_bounds__(256) void peg_kernel(char* ws){
  __shared__ __align__(16) f16 tile[3][32][256];
  const f16* h1T = (const f16*)(ws + WS_H1T);
  const f16* pegq = (const f16*)(ws + WS_PEGQ);
  const float* pb  = (const float*)(ws + WS_PEG_B);
  const float* inv1 = (const float*)(ws + WS_BN1_INV);
  const float* bt1  = (const float*)(ws + WS_BN1_BETA);
  f16* h2T = (f16*)(ws + WS_H2T);

  int tid = threadIdx.x;
  int b = blockIdx.x >> 5, h = blockIdx.x & 31;

  #pragma unroll
  for (int r = 0; r < 3; ++r){
    int hh = h + r - 1;
    #pragma unroll
    for (int i = 0; i < 4; ++i){
      int chunk = tid + (i << 8);
      int px = chunk >> 5, cg = chunk & 31;
      u32x4 d = {0u, 0u, 0u, 0u};
      if ((u32)hh < 32u)
        d = *(const u32x4*)(h1T + (((size_t)(b << 10) + (hh << 5) + px) << 8) + (cg << 3));
      *(u32x4*)(&tile[r][px][cg << 3]) = d;
    }
  }
  __syncthreads();

  int c0 = (tid & 31) << 3;
  int q  = tid >> 5;
  float acc[4][8];
  #pragma unroll
  for (int i = 0; i < 4; ++i)
    #pragma unroll
    for (int j = 0; j < 8; ++j) acc[i][j] = pb[c0 + j];

  #pragma unroll
  for (int ky = 0; ky < 3; ++ky){
    #pragma unroll
    for (int kx = 0; kx < 3; ++kx){
      f16x8 wv = *(const f16x8*)(pegq + ((ky * 3 + kx) << 8) + c0);
      #pragma unroll
      for (int i = 0; i < 4; ++i){
        int ww = (q << 2) + i + kx - 1;
        if ((u32)ww < 32u){
          f16x8 v = *(const f16x8*)(&tile[ky][ww][c0]);
          #pragma unroll
          for (int j = 0; j < 8; ++j) acc[i][j] += (float)v[j] * (float)wv[j];
        }
      }
    }
  }

  f32x4 iv0 = *(const f32x4*)(inv1 + c0), iv1 = *(const f32x4*)(inv1 + c0 + 4);
  f32x4 bt0 = *(const f32x4*)(bt1 + c0),  bt1v = *(const f32x4*)(bt1 + c0 + 4);
  #pragma unroll
  for (int i = 0; i < 4; ++i){
    f16x8 o;
    #pragma unroll
    for (int j = 0; j < 8; ++j){
      float ivj = (j < 4) ? iv0[j] : iv1[j - 4];
      float btj = (j < 4) ? bt0[j] : bt1v[j - 4];
      o[j] = (f16)fmaxf(acc[i][j] * ivj + btj, 0.0f);
    }
    int p = (h << 5) + (q << 2) + i;
    *(f16x8*)(h2T + (((size_t)(b << 10) + p) << 8) + c0) = o;
  }
}

// ---- conv23 (FUSED): conv2 (h3 in LDS) + conv3 + bn3 + residual + relu.
// Phase 2: 16 co-tiles of 64, w3 double-buffered (stage hides under MFMA). ----
__global__ __launch_bounds__(512) void conv23_kernel(const float* __restrict__ x,
                                                     float* __restrict__ out, char* ws){
  __shared__ __align__(16) char lds[137216];
  const f16* h2T = (const f16*)(ws + WS_H2T);
  const f16* w2q = (const f16*)(ws + WS_W2Q);
  const f16* w3q = (const f16*)(ws + WS_W3Q);
  const float* inv2 = (const float*)(ws + WS_BN2_INV);
  const float* bt2  = (const float*)(ws + WS_BN2_BETA);
  const float* inv3 = (const float*)(ws + WS_BN3_INV);
  const float* bt3  = (const float*)(ws + WS_BN3_BETA);

  int tid = threadIdx.x, bid = blockIdx.x;
  int b = bid >> 3, mt = bid & 7;
  int h0 = mt << 2;
  int m0 = mt << 7;
  int l = tid & 63, wid = tid >> 6, wm = wid >> 2, wn = wid & 3;
  int lr = l & 15, lg = l >> 4;
  int rk = lr & 7;
  char* A = lds;
  char* B0 = lds + 104448;
  char* B1 = lds + 104448 + 16384;

  // ===== phase 1: conv2 (A staged once, low-bit swizzle; B dbuf) =====
  for (int chunk = tid; chunk < 6528; chunk += 512){
    int r = chunk / 1088;
    int rem = chunk - r * 1088;
    int cc = rem >> 5, slot = rem & 31;
    int hh = h0 - 1 + r, wwp = cc - 1;
    u32x4 d = {0u, 0u, 0u, 0u};
    if ((u32)hh < 32u && (u32)wwp < 32u)
      d = *(const u32x4*)(h2T + (((size_t)(b << 10) + (hh << 5) + wwp) << 8) + (slot << 3));
    int sw = slot ^ (cc & 7);
    *(u32x4*)(A + ((r * 34 + cc) << 9) + (sw << 4)) = d;
  }
  #pragma unroll
  for (int i = 0; i < 2; ++i){
    int chunk = tid + (i << 9);
    int co = chunk >> 2, slot = chunk & 3;
    u32x4 d = *(const u32x4*)(w2q + (co << 8) + (slot << 3));
    *(u32x4*)(B0 + (co << 6) + (SWZ(co, slot) << 4)) = d;
  }
  __syncthreads();

  f32x4 acc[4][4] = {};
  for (int tap = 0; tap < 9; ++tap){
    int dy = tap / 3 - 1, dx = tap % 3 - 1;
    int rowbase[4], key[4];
    #pragma unroll
    for (int mf = 0; mf < 4; ++mf){
      int p = (wm << 6) + (mf << 4) + lr;
      int rr = (p >> 5) + dy + 1;
      int cc = (p & 31) + dx + 1;
      rowbase[mf] = (rr * 34 + cc) << 9;
      key[mf] = cc & 7;
    }
    #pragma unroll 2
    for (int ks = 0; ks < 8; ++ks){
      int t = (tap << 3) + ks;
      u32x4 st[2];
      int have = (t < 71);
      int t1 = t + 1, wtap = t1 >> 3, wks = t1 & 7;
      const f16* srcb = w2q + wtap * 65536 + (wks << 5);
      if (have){
        #pragma unroll
        for (int i = 0; i < 2; ++i){
          int chunk = tid + (i << 9);
          int co = chunk >> 2, slot = chunk & 3;
          st[i] = *(const u32x4*)(srcb + (co << 8) + (slot << 3));
        }
      }
      const char* bs = (t & 1) ? B1 : B0;
      f16x8 a[4], bb[4];
      int sl = (ks << 2) | lg;
      #pragma unroll
      for (int mf = 0; mf < 4; ++mf)
        a[mf] = *(const f16x8*)(A + rowbase[mf] + ((sl ^ key[mf]) << 4));
      #pragma unroll
      for (int nf = 0; nf < 4; ++nf){
        int row = (wn << 6) + (nf << 4) + lr;
        bb[nf] = *(const f16x8*)(bs + (row << 6) + (SWZ(row, lg) << 4));
      }
      #pragma unroll
      for (int mf = 0; mf < 4; ++mf)
        #pragma unroll
        for (int nf = 0; nf < 4; ++nf)
          acc[mf][nf] = __builtin_amdgcn_mfma_f32_16x16x32_f16(a[mf], bb[nf], acc[mf][nf], 0, 0, 0);
      if (have){
        char* bd = (t1 & 1) ? B1 : B0;
        #pragma unroll
        for (int i = 0; i < 2; ++i){
          int chunk = tid + (i << 9);
          int co = chunk >> 2, slot = chunk & 3;
          *(u32x4*)(bd + (co << 6) + (SWZ(co, slot) << 4)) = st[i];
        }
      }
      __syncthreads();
    }
  }

  // ===== h3 = bn2+relu(acc) -> LDS [128 px][256 c], low-bit swizzle =====
  #pragma unroll
  for (int mf = 0; mf < 4; ++mf){
    #pragma unroll
    for (int nf = 0; nf < 4; ++nf){
      int c = (wn << 6) + (nf << 4) + lr;
      float iv = inv2[c], bt = bt2[c];
      int slot = c >> 3, off = (c & 7) << 1;
      #pragma unroll
      for (int r = 0; r < 4; ++r){
        int px = (wm << 6) + (mf << 4) + (lg << 2) + r;
        float f = fmaxf(acc[mf][nf][r] * iv + bt, 0.0f);
        *(f16*)(lds + (px << 9) + ((slot ^ (px & 7)) << 4) + off) = (f16)f;
      }
    }
  }

  // ===== phase 2: conv3, 16 co-tiles of 64; w3 double-buffered =====
  // wave grid: wc = co-half (0..1), wp = px-quarter (0..3)
  int wc = wid >> 2, wp = wid & 3;
  char* W3 = lds + 65536;
  // prologue: stage w3 tile 0 into buf0 (barrier also publishes h3)
  #pragma unroll
  for (int i = 0; i < 4; ++i){
    int chunk = tid + (i << 9);
    int row = chunk >> 5, slot = chunk & 31;
    u32x4 d = *(const u32x4*)(w3q + ((size_t)row << 8) + (slot << 3));
    *(u32x4*)(W3 + (row << 9) + ((slot ^ (row & 7)) << 4)) = d;
  }
  __syncthreads();

  for (int cot = 0; cot < 16; ++cot){
    const char* cur = W3 + ((cot & 1) << 15);
    char* nxt = W3 + (((cot + 1) & 1) << 15);
    // early-issue next w3 tile global loads
    u32x4 st[4];
    int have = (cot < 15);
    if (have){
      const f16* srcb = w3q + (((size_t)(cot + 1)) << 14);  // (cot+1)*64*256
      #pragma unroll
      for (int i = 0; i < 4; ++i){
        int chunk = tid + (i << 9);
        int row = chunk >> 5, slot = chunk & 31;
        st[i] = *(const u32x4*)(srcb + ((size_t)row << 8) + (slot << 3));
      }
    }
    // MFMA on current w3 tile
    f32x4 acc2[2][2] = {};
    #pragma unroll
    for (int ks = 0; ks < 8; ++ks){
      int sl = ((ks << 2) | lg) ^ rk;
      f16x8 a[2], bb[2];
      #pragma unroll
      for (int mf = 0; mf < 2; ++mf){
        int row = (wc << 5) + (mf << 4) + lr;
        a[mf] = *(const f16x8*)(cur + (row << 9) + (sl << 4));
      }
      #pragma unroll
      for (int nf = 0; nf < 2; ++nf){
        int row = (wp << 5) + (nf << 4) + lr;
        bb[nf] = *(const f16x8*)(lds + (row << 9) + (sl << 4));
      }
      #pragma unroll
      for (int mf = 0; mf < 2; ++mf)
        #pragma unroll
        for (int nf = 0; nf < 2; ++nf)
          acc2[mf][nf] = __builtin_amdgcn_mfma_f32_16x16x32_f16(a[mf], bb[nf], acc2[mf][nf], 0, 0, 0);
    }
    // late write of staged w3
    if (have){
      #pragma unroll
      for (int i = 0; i < 4; ++i){
        int chunk = tid + (i << 9);
        int row = chunk >> 5, slot = chunk & 31;
        *(u32x4*)(nxt + (row << 9) + ((slot ^ (row & 7)) << 4)) = st[i];
      }
    }
    // epilogue: bn3 + residual + relu -> out
    #pragma unroll
    for (int mf = 0; mf < 2; ++mf){
      int co0 = (cot << 6) + (wc << 5) + (mf << 4) + (lg << 2);
      f32x4 iv = *(const f32x4*)(inv3 + co0);
      f32x4 bt = *(const f32x4*)(bt3 + co0);
      float xr[8];
      #pragma unroll
      for (int nf = 0; nf < 2; ++nf){
        int px = (wp << 5) + (nf << 4) + lr;
        #pragma unroll
        for (int r = 0; r < 4; ++r)
          xr[(nf << 2) + r] = x[(((size_t)(b << 10) + co0 + r) << 10) + m0 + px];
      }
      #pragma unroll
      for (int nf = 0; nf < 2; ++nf){
        int px = (wp << 5) + (nf << 4) + lr;
        #pragma unroll
        for (int r = 0; r < 4; ++r){
          size_t idx = (((size_t)(b << 10) + co0 + r) << 10) + m0 + px;
          float z = acc2[mf][nf][r] * iv[r] + bt[r] + xr[(nf << 2) + r];
          float rr = fmaxf(z, 0.0f);
          if (badf(z)) rr = 512.0f;
          out[idx] = rr;
        }
      }
    }
    __syncthreads();
  }
}

extern "C" void kernel_launch(void* const* d_in, const int* in_sizes, int n_in,
                              void* d_out, int out_size, void* d_ws, size_t ws_size,
                              hipStream_t stream){
  const float* x    = (const float*)d_in[0];
  const float* w1   = (const float*)d_in[1];
  const float* pegw = (const float*)d_in[2];
  const float* pegb = (const float*)d_in[3];
  const float* w2   = (const float*)d_in[4];
  const float* w3   = (const float*)d_in[5];
  const float* g1 = (const float*)d_in[6];
  const float* b1 = (const float*)d_in[7];
  const float* m1 = (const float*)d_in[8];
  const float* v1 = (const float*)d_in[9];
  const float* g2 = (const float*)d_in[10];
  const float* b2 = (const float*)d_in[11];
  const float* m2 = (const float*)d_in[12];
  const float* v2 = (const float*)d_in[13];
  const float* g3 = (const float*)d_in[14];
  const float* b3 = (const float*)d_in[15];
  const float* m3 = (const float*)d_in[16];
  const float* v3 = (const float*)d_in[17];
  char* ws = (char*)d_ws;

  prep_kernel<<<4368, 256, 0, stream>>>(w1, pegw, pegb, w2, w3,
                                        g1, b1, m1, v1, g2, b2, m2, v2,
                                        g3, b3, m3, v3, ws);
  conv1_kernel<<<256, 512, 0, stream>>>(x, ws);
  peg_kernel<<<1024, 256, 0, stream>>>(ws);
  conv23_kernel<<<256, 512, 0, stream>>>(x, (float*)d_out, ws);
}